// Round 5
// baseline (748.402 us; speedup 1.0000x reference)
//
#include <hip/hip_runtime.h>
#include <stdint.h>

#define NN 50000
#define NE 800000
#define HID 128
#define NG 64
#define BN_EPS 1e-5f
#define SCAN_BLOCKS 196  // 196*256 = 50176 >= NN
#define GEMM_BLOCKS ((NN + 127) / 128)
#define SC_NB 8                                  // buckets (== XCD count)
#define SC_BSZ ((NN + SC_NB - 1) / SC_NB)        // 6250 nodes per bucket
#define SC_CHUNK 4096                            // edges per block
#define SC_CHUNKS ((NE + SC_CHUNK - 1) / SC_CHUNK)
// probe repeat counts (instrumented round: probes are correctness-neutral,
// write scratch only, and exist to cross the ~44us top-5 visibility floor)
#define PR_AGG 2
#define PR_GEMM 2
#define PR_SCAT 3
#define PR_HIST 4

typedef __bf16 bf16x8 __attribute__((ext_vector_type(8)));
typedef float floatx4 __attribute__((ext_vector_type(4)));

__device__ __forceinline__ float b2f(unsigned short u) {
    union { unsigned int i; float f; } x; x.i = ((unsigned int)u) << 16; return x.f;
}
__device__ __forceinline__ float blo(unsigned int d) { return __uint_as_float(d << 16); }
__device__ __forceinline__ float bhi(unsigned int d) { return __uint_as_float(d & 0xffff0000u); }
__device__ __forceinline__ unsigned short f2b(float f) {
    union { float f; unsigned int i; } x; x.f = f; unsigned int i = x.i;
    if ((i & 0x7f800000u) == 0x7f800000u) return (unsigned short)(i >> 16); // inf/nan
    return (unsigned short)((i + 0x7fffu + ((i >> 16) & 1u)) >> 16);        // RNE
}
__device__ __forceinline__ unsigned int pack2(float f0, float f1) {
    return (((unsigned int)f2b(f1)) << 16) | f2b(f0);
}
// folded BN scale/shift for column c (from raw sums)
__device__ __forceinline__ float2 bn_pair(const float* __restrict__ bnstat,
                                          const float* __restrict__ gamma,
                                          const float* __restrict__ beta, int c) {
    float mu = bnstat[c] * (1.f / NN);
    float var = bnstat[128 + c] * (1.f / NN) - mu * mu;
    float s = gamma[c] * rsqrtf(var + BN_EPS);
    return make_float2(s, beta[c] - mu * s);
}

// ---------------- setup (incl. weight prep) ----------------
__global__ void k_setup(const float* __restrict__ x, unsigned short* xb, int* deg,
                        int* gstart, int* gend, float* bnstats,
                        float* pool_sum, int* pool_max,
                        const float* __restrict__ Wl0, const float* __restrict__ Wr0,
                        const float* __restrict__ Wl1, const float* __restrict__ Wr1,
                        const float* __restrict__ Wl2, const float* __restrict__ Wr2,
                        unsigned short* Bp) {
    int i = blockIdx.x * 256 + threadIdx.x;
    if (i < NN * 64) {
        float2 v = ((const float2*)x)[i];
        ((unsigned int*)xb)[i] = pack2(v.x, v.y);
    }
    if (i < NN) deg[i] = 0;
    if (i < NG) { gstart[i] = NN; gend[i] = -1; }  // empty-graph-safe defaults
    if (i < 3 * 256) bnstats[i] = 0.f;
    if (i < NG * HID) { pool_sum[i] = 0.f; pool_max[i] = 0; }
    if (i < 3 * 32768) {
        int layer = i >> 15;
        int r = i & 32767;
        int nt = r >> 12, kk = (r >> 9) & 7, l = (r >> 3) & 63, j = r & 7;
        int k = kk * 32 + (l >> 4) * 8 + j;
        int n = nt * 16 + (l & 15);
        const float* Wl = layer == 0 ? Wl0 : (layer == 1 ? Wl1 : Wl2);
        const float* Wr = layer == 0 ? Wr0 : (layer == 1 ? Wr1 : Wr2);
        Bp[i] = f2b((k < 128) ? Wl[k * 128 + n] : Wr[(k - 128) * 128 + n]);
    }
}

// bucketized degree histogram: block = (chunk, bucket); atomics stay XCD-local
__global__ void k_hist(const int* __restrict__ dst, int* deg) {
    int bucket = blockIdx.x & (SC_NB - 1);
    int chunk = blockIdx.x / SC_NB;
    int lo = bucket * SC_BSZ, hi = lo + SC_BSZ;
    int base = chunk * SC_CHUNK;
#pragma unroll
    for (int i = 0; i < SC_CHUNK / 256; ++i) {
        int e = base + i * 256 + threadIdx.x;
        if (e < NE) {
            int d = dst[e];
            if (d >= lo && d < hi) atomicAdd(&deg[d], 1);
        }
    }
}

// ---------------- hierarchical exclusive scan of deg (+ graph bounds) ----------------
__global__ void k_scan1(const int* __restrict__ deg, int* blocksum,
                        const int* __restrict__ batch, int* gstart, int* gend) {
    __shared__ int lds[256];
    int t = threadIdx.x, i = blockIdx.x * 256 + t;
    lds[t] = (i < NN) ? deg[i] : 0;
    if (i < NN) {
        int g = batch[i];
        if (i == 0 || batch[i - 1] != g) gstart[g] = i;
        if (i == NN - 1 || batch[i + 1] != g) gend[g] = i;
    }
    __syncthreads();
    for (int off = 128; off > 0; off >>= 1) {
        if (t < off) lds[t] += lds[t + off];
        __syncthreads();
    }
    if (t == 0) blocksum[blockIdx.x] = lds[0];
}

// scan23: every block redundantly scans the 196 block sums, then emits its own
// 256 element offsets. Also initializes the 3 probe-scatter cursor copies.
__global__ void k_scan23(const int* __restrict__ deg, const int* __restrict__ blocksum,
                         int* row_start, int* cursor,
                         int* pc0, int* pc1, int* pc2) {
    __shared__ int bs[256];
    __shared__ int lds[256];
    int t = threadIdx.x;
    bs[t] = (t < SCAN_BLOCKS) ? blocksum[t] : 0;
    __syncthreads();
    for (int off = 1; off < 256; off <<= 1) {
        int u = (t >= off) ? bs[t - off] : 0;
        __syncthreads();
        bs[t] += u;
        __syncthreads();
    }
    int blockoff = (blockIdx.x == 0) ? 0 : bs[blockIdx.x - 1];  // exclusive prefix
    int i = blockIdx.x * 256 + t;
    int v = (i < NN) ? deg[i] : 0;
    lds[t] = v;
    __syncthreads();
    for (int off = 1; off < 256; off <<= 1) {
        int u = (t >= off) ? lds[t - off] : 0;
        __syncthreads();
        lds[t] += u;
        __syncthreads();
    }
    if (i < NN) {
        int ex = blockoff + lds[t] - v;
        row_start[i] = ex;
        cursor[i] = ex;
        pc0[i] = ex; pc1[i] = ex; pc2[i] = ex;
    }
    if (blockIdx.x == 0 && t == 0) row_start[NN] = NE;  // all dst in [0,NN)
}

// XCD-bucketized scatter: writes for one 400KB col slice stay in one XCD L2
__global__ void k_scatter(const int* __restrict__ src, const int* __restrict__ dst,
                          int* cursor, int* col) {
    int bucket = blockIdx.x & (SC_NB - 1);
    int chunk = blockIdx.x / SC_NB;
    int lo = bucket * SC_BSZ, hi = lo + SC_BSZ;
    int base = chunk * SC_CHUNK;
#pragma unroll
    for (int i = 0; i < SC_CHUNK / 256; ++i) {
        int e = base + i * 256 + threadIdx.x;
        if (e < NE) {
            int d = dst[e];
            if (d >= lo && d < hi) {
                int p = atomicAdd(&cursor[d], 1);
                col[p] = src[e];
            }
        }
    }
}

// ---------------- per-layer kernels (proven 402us versions) ----------------
__global__ void k_agg(const unsigned short* __restrict__ h, const int* __restrict__ row_start,
                      const int* __restrict__ col, const float* __restrict__ bnstat,
                      const float* __restrict__ gamma, const float* __restrict__ beta,
                      unsigned short* __restrict__ agg) {
    int wid = threadIdx.x >> 6, lane = threadIdx.x & 63;
    int slot = lane >> 4, sub = lane & 15;
    int node = (blockIdx.x * 4 + wid) * 4 + slot;  // 3125*4*4 == 50000 exactly
    int s = row_start[node], e = row_start[node + 1];
    bool ap = bnstat != nullptr;
    float scv[8], shv[8];
    if (ap) {
#pragma unroll
        for (int i = 0; i < 8; ++i) {
            float2 p = bn_pair(bnstat, gamma, beta, sub * 8 + i);
            scv[i] = p.x; shv[i] = p.y;
        }
    }
    auto tf = [&](float f, int i) -> float {
        return ap ? fmaxf(f * scv[i] + shv[i], 0.f) : f;
    };
    const uint4* h4 = (const uint4*)h;  // one row = 16 uint4 (256B)
    float a0 = 0.f, a1 = 0.f, a2 = 0.f, a3 = 0.f, a4 = 0.f, a5 = 0.f, a6 = 0.f, a7 = 0.f;
    int j = s;
    for (; j + 4 <= e; j += 4) {
        int u0 = col[j], u1 = col[j + 1], u2 = col[j + 2], u3 = col[j + 3];
        uint4 v0 = h4[(size_t)u0 * 16 + sub];
        uint4 v1 = h4[(size_t)u1 * 16 + sub];
        uint4 v2 = h4[(size_t)u2 * 16 + sub];
        uint4 v3 = h4[(size_t)u3 * 16 + sub];
        a0 += (tf(blo(v0.x), 0) + tf(blo(v1.x), 0)) + (tf(blo(v2.x), 0) + tf(blo(v3.x), 0));
        a1 += (tf(bhi(v0.x), 1) + tf(bhi(v1.x), 1)) + (tf(bhi(v2.x), 1) + tf(bhi(v3.x), 1));
        a2 += (tf(blo(v0.y), 2) + tf(blo(v1.y), 2)) + (tf(blo(v2.y), 2) + tf(blo(v3.y), 2));
        a3 += (tf(bhi(v0.y), 3) + tf(bhi(v1.y), 3)) + (tf(bhi(v2.y), 3) + tf(bhi(v3.y), 3));
        a4 += (tf(blo(v0.z), 4) + tf(blo(v1.z), 4)) + (tf(blo(v2.z), 4) + tf(blo(v3.z), 4));
        a5 += (tf(bhi(v0.z), 5) + tf(bhi(v1.z), 5)) + (tf(bhi(v2.z), 5) + tf(bhi(v3.z), 5));
        a6 += (tf(blo(v0.w), 6) + tf(blo(v1.w), 6)) + (tf(blo(v2.w), 6) + tf(blo(v3.w), 6));
        a7 += (tf(bhi(v0.w), 7) + tf(bhi(v1.w), 7)) + (tf(bhi(v2.w), 7) + tf(bhi(v3.w), 7));
    }
    for (; j < e; ++j) {
        int u = col[j];
        uint4 v = h4[(size_t)u * 16 + sub];
        a0 += tf(blo(v.x), 0);  a1 += tf(bhi(v.x), 1);
        a2 += tf(blo(v.y), 2);  a3 += tf(bhi(v.y), 3);
        a4 += tf(blo(v.z), 4);  a5 += tf(bhi(v.z), 5);
        a6 += tf(blo(v.w), 6);  a7 += tf(bhi(v.w), 7);
    }
    float inv = (e > s) ? 1.f / (float)(e - s) : 0.f;
    uint4 o;
    o.x = pack2(a0 * inv, a1 * inv);
    o.y = pack2(a2 * inv, a3 * inv);
    o.z = pack2(a4 * inv, a5 * inv);
    o.w = pack2(a6 * inv, a7 * inv);
    ((uint4*)agg)[(size_t)node * 16 + sub] = o;
}

// apply folded norm (from LDS tables) to a bf16x8 fragment (cols cbase..cbase+7)
__device__ __forceinline__ bf16x8 norm8(bf16x8 v, const float* sc, const float* sh, int cbase) {
    union { bf16x8 v; unsigned short u[8]; } in; in.v = v;
    union { unsigned int u[4]; bf16x8 v; } out;
#pragma unroll
    for (int i = 0; i < 4; ++i) {
        float f0 = fmaxf(b2f(in.u[2 * i]) * sc[cbase + 2 * i] + sh[cbase + 2 * i], 0.f);
        float f1 = fmaxf(b2f(in.u[2 * i + 1]) * sc[cbase + 2 * i + 1] + sh[cbase + 2 * i + 1], 0.f);
        out.u[i] = pack2(f0, f1);
    }
    return out.v;
}

// buf[M,128] <- [buf | norm(h)][M,256] @ Wcat[256,128], bf16 in-place
__global__ void __launch_bounds__(256) k_gemm(unsigned short* buf,
                                              const unsigned short* h,
                                              const unsigned short* __restrict__ Bp,
                                              const float* __restrict__ pbnstat,
                                              const float* __restrict__ pgamma,
                                              const float* __restrict__ pbeta,
                                              float* bnstat) {
    __shared__ unsigned short Bs[32768];  // 64KB B fragments; reused for stat reduce
    __shared__ float s_sc[128], s_sh[128];
    int t = threadIdx.x;
    {
        const uint4* s4 = (const uint4*)Bp;
        uint4* d4 = (uint4*)Bs;
        for (int i = t; i < 4096; i += 256) d4[i] = s4[i];
    }
    bool ap = pbnstat != nullptr;
    if (ap && t < 128) {
        float2 p = bn_pair(pbnstat, pgamma, pbeta, t);
        s_sc[t] = p.x; s_sh[t] = p.y;
    }
    __syncthreads();
    int wid = t >> 6, lane = t & 63;
    int m = lane & 15, q = lane >> 4;
    int mbase = blockIdx.x * 128 + wid * 32;
    bool active = mbase < NN;
    float s8[8] = {0, 0, 0, 0, 0, 0, 0, 0};
    float ss8[8] = {0, 0, 0, 0, 0, 0, 0, 0};
    if (active) {
        int row0 = mbase + m;
        int row1 = min(mbase + 16 + m, NN - 1);  // clamp tail (stores masked below)
        const bf16x8* Abuf = (const bf16x8*)buf;
        const bf16x8* Ah = (const bf16x8*)h;
        size_t b0 = (size_t)row0 * 16, b1 = (size_t)row1 * 16;
        bf16x8 af0[8], af1[8];
#pragma unroll
        for (int kk = 0; kk < 4; ++kk) {
            af0[kk] = Abuf[b0 + kk * 4 + q];
            af1[kk] = Abuf[b1 + kk * 4 + q];
            bf16x8 h0 = Ah[b0 + kk * 4 + q];
            bf16x8 h1 = Ah[b1 + kk * 4 + q];
            if (ap) {
                int cb = kk * 32 + q * 8;
                h0 = norm8(h0, s_sc, s_sh, cb);
                h1 = norm8(h1, s_sc, s_sh, cb);
            }
            af0[4 + kk] = h0;
            af1[4 + kk] = h1;
        }
        const bf16x8* B = (const bf16x8*)Bs;
        floatx4 acc[2][8];
#pragma unroll
        for (int mt = 0; mt < 2; ++mt)
#pragma unroll
            for (int nt = 0; nt < 8; ++nt) acc[mt][nt] = (floatx4){0.f, 0.f, 0.f, 0.f};
#pragma unroll
        for (int kk = 0; kk < 8; ++kk) {
#pragma unroll
            for (int nt = 0; nt < 8; ++nt) {
                bf16x8 b = B[(nt * 8 + kk) * 64 + lane];
                acc[0][nt] = __builtin_amdgcn_mfma_f32_16x16x32_bf16(af0[kk], b, acc[0][nt], 0, 0, 0);
                acc[1][nt] = __builtin_amdgcn_mfma_f32_16x16x32_bf16(af1[kk], b, acc[1][nt], 0, 0, 0);
            }
        }
#pragma unroll
        for (int mt = 0; mt < 2; ++mt)
#pragma unroll
            for (int nt = 0; nt < 8; ++nt) {
                int c = nt * 16 + m;  // C/D: col = lane&15
#pragma unroll
                for (int reg = 0; reg < 4; ++reg) {
                    int r = mbase + mt * 16 + q * 4 + reg;  // C/D: row = quad*4+reg
                    if (r < NN) {
                        float v = acc[mt][nt][reg];
                        buf[(size_t)r * 128 + c] = f2b(v);
                        s8[nt] += v;
                        ss8[nt] += v * v;
                    }
                }
            }
#pragma unroll
        for (int nt = 0; nt < 8; ++nt) {
            s8[nt] += __shfl_xor(s8[nt], 16, 64);  s8[nt] += __shfl_xor(s8[nt], 32, 64);
            ss8[nt] += __shfl_xor(ss8[nt], 16, 64); ss8[nt] += __shfl_xor(ss8[nt], 32, 64);
        }
    }
    __syncthreads();  // all waves done reading Bs
    float* stf = (float*)Bs;
    if (t < 256) stf[t] = 0.f;
    __syncthreads();
    if (active && lane < 16) {
#pragma unroll
        for (int nt = 0; nt < 8; ++nt) {
            int c = nt * 16 + m;
            atomicAdd(&stf[c], s8[nt]);
            atomicAdd(&stf[128 + c], ss8[nt]);
        }
    }
    __syncthreads();
    if (t < 256) atomicAdd(&bnstat[t], stf[t]);
}

// ---------------- pooling (folded norm inline) + head ----------------
__global__ void k_pool(const unsigned short* __restrict__ h, const int* __restrict__ gstart,
                       const int* __restrict__ gend, const float* __restrict__ bnstat,
                       const float* __restrict__ gamma, const float* __restrict__ beta,
                       float* pool_sum, int* pool_max) {
    int g = blockIdx.x >> 3, chunk = blockIdx.x & 7;
    int s = gstart[g], e = gend[g];
    if (s > e) return;
    int cnt = e - s + 1;
    int per = (cnt + 7) >> 3;
    int r0 = s + chunk * per;
    int r1 = min(r0 + per, e + 1);
    int c = threadIdx.x & 127, half = threadIdx.x >> 7;
    float2 pr = bn_pair(bnstat, gamma, beta, c);
    float sm = 0.f, mx = 0.f;  // post-relu values are >= 0
    for (int r = r0 + half; r < r1; r += 2) {
        float v = fmaxf(b2f(h[(size_t)r * 128 + c]) * pr.x + pr.y, 0.f);
        sm += v;
        mx = fmaxf(mx, v);
    }
    atomicAdd(&pool_sum[g * 128 + c], sm);
    atomicMax(&pool_max[g * 128 + c], __float_as_int(mx));  // valid for >=0 floats
}

__global__ void __launch_bounds__(128) k_head(
    const float* __restrict__ pool_sum, const int* __restrict__ pool_max,
    const int* __restrict__ gstart, const int* __restrict__ gend,
    const float* __restrict__ gfeats,
    const float* __restrict__ W1, const float* __restrict__ bs1,
    const float* __restrict__ W2, const float* __restrict__ bs2,
    const float* __restrict__ W3, const float* __restrict__ bs3,
    float* out) {
    __shared__ float m[288];
    __shared__ float o1[128];
    __shared__ float o2[64];
    int g = blockIdx.x, t = threadIdx.x;
    int s = gstart[g], e = gend[g];
    int cint = e - s + 1;
    float cnt = (float)(cint < 1 ? 1 : cint);
    if (t < 128) {
        m[t] = pool_sum[g * 128 + t] / cnt;
        m[128 + t] = __int_as_float(pool_max[g * 128 + t]);
    }
    if (t < 32) m[256 + t] = gfeats[g * 32 + t];
    __syncthreads();
    float acc = bs1[t];
    for (int k = 0; k < 288; ++k) acc += m[k] * W1[k * 128 + t];
    o1[t] = fmaxf(acc, 0.f);
    __syncthreads();
    if (t < 64) {
        float a2 = bs2[t];
        for (int k = 0; k < 128; ++k) a2 += o1[k] * W2[k * 64 + t];
        o2[t] = fmaxf(a2, 0.f);
    }
    __syncthreads();
    if (t < 64) {
        float p = o2[t] * W3[t];
#pragma unroll
        for (int off = 32; off; off >>= 1) p += __shfl_down(p, off, 64);
        if (t == 0) out[g] = p + bs3[0];
    }
}

// ================= PROBES (write scratch only; appended after k_head) =======
// p_agg: k_agg body x PR_AGG into scratch. t_agg = dur/PR_AGG.
__global__ void p_agg(const unsigned short* h, const int* row_start,
                      const int* col, const float* bnstat,
                      const float* gamma, const float* beta,
                      unsigned short* scratch) {
    int wid = threadIdx.x >> 6, lane = threadIdx.x & 63;
    int slot = lane >> 4, sub = lane & 15;
    int node = (blockIdx.x * 4 + wid) * 4 + slot;
    int s = row_start[node], e = row_start[node + 1];
    float scv[8], shv[8];
#pragma unroll
    for (int i = 0; i < 8; ++i) {
        float2 p = bn_pair(bnstat, gamma, beta, sub * 8 + i);
        scv[i] = p.x; shv[i] = p.y;
    }
    auto tf = [&](float f, int i) -> float { return fmaxf(f * scv[i] + shv[i], 0.f); };
    const uint4* h4 = (const uint4*)h;
#pragma unroll 1
    for (int rep = 0; rep < PR_AGG; ++rep) {
        float a0 = 0.f, a1 = 0.f, a2 = 0.f, a3 = 0.f, a4 = 0.f, a5 = 0.f, a6 = 0.f, a7 = 0.f;
        int j = s;
        for (; j + 4 <= e; j += 4) {
            int u0 = col[j], u1 = col[j + 1], u2 = col[j + 2], u3 = col[j + 3];
            uint4 v0 = h4[(size_t)u0 * 16 + sub];
            uint4 v1 = h4[(size_t)u1 * 16 + sub];
            uint4 v2 = h4[(size_t)u2 * 16 + sub];
            uint4 v3 = h4[(size_t)u3 * 16 + sub];
            a0 += (tf(blo(v0.x), 0) + tf(blo(v1.x), 0)) + (tf(blo(v2.x), 0) + tf(blo(v3.x), 0));
            a1 += (tf(bhi(v0.x), 1) + tf(bhi(v1.x), 1)) + (tf(bhi(v2.x), 1) + tf(bhi(v3.x), 1));
            a2 += (tf(blo(v0.y), 2) + tf(blo(v1.y), 2)) + (tf(blo(v2.y), 2) + tf(blo(v3.y), 2));
            a3 += (tf(bhi(v0.y), 3) + tf(bhi(v1.y), 3)) + (tf(bhi(v2.y), 3) + tf(bhi(v3.y), 3));
            a4 += (tf(blo(v0.z), 4) + tf(blo(v1.z), 4)) + (tf(blo(v2.z), 4) + tf(blo(v3.z), 4));
            a5 += (tf(bhi(v0.z), 5) + tf(bhi(v1.z), 5)) + (tf(bhi(v2.z), 5) + tf(bhi(v3.z), 5));
            a6 += (tf(blo(v0.w), 6) + tf(blo(v1.w), 6)) + (tf(blo(v2.w), 6) + tf(blo(v3.w), 6));
            a7 += (tf(bhi(v0.w), 7) + tf(bhi(v1.w), 7)) + (tf(bhi(v2.w), 7) + tf(bhi(v3.w), 7));
        }
        for (; j < e; ++j) {
            int u = col[j];
            uint4 v = h4[(size_t)u * 16 + sub];
            a0 += tf(blo(v.x), 0);  a1 += tf(bhi(v.x), 1);
            a2 += tf(blo(v.y), 2);  a3 += tf(bhi(v.y), 3);
            a4 += tf(blo(v.z), 4);  a5 += tf(bhi(v.z), 5);
            a6 += tf(blo(v.w), 6);  a7 += tf(bhi(v.w), 7);
        }
        float inv = (e > s) ? 1.f / (float)(e - s) : 0.f;
        uint4 o;
        o.x = pack2(a0 * inv, a1 * inv);
        o.y = pack2(a2 * inv, a3 * inv);
        o.z = pack2(a4 * inv, a5 * inv);
        o.w = pack2(a6 * inv, a7 * inv);
        ((uint4*)scratch)[(size_t)node * 16 + sub] = o;
    }
}

// p_gemm: full k_gemm body x PR_GEMM (incl. LDS staging), scratch out/stat.
__global__ void __launch_bounds__(256) p_gemm(const unsigned short* buf,
                                              const unsigned short* h,
                                              const unsigned short* Bp,
                                              const float* pbnstat,
                                              const float* pgamma,
                                              const float* pbeta,
                                              float* sbnstat,
                                              unsigned short* sout) {
    __shared__ unsigned short Bs[32768];
    __shared__ float s_sc[128], s_sh[128];
    int t = threadIdx.x;
#pragma unroll 1
    for (int rep = 0; rep < PR_GEMM; ++rep) {
        {
            const uint4* s4 = (const uint4*)Bp;
            uint4* d4 = (uint4*)Bs;
            for (int i = t; i < 4096; i += 256) d4[i] = s4[i];
        }
        if (t < 128) {
            float2 p = bn_pair(pbnstat, pgamma, pbeta, t);
            s_sc[t] = p.x; s_sh[t] = p.y;
        }
        __syncthreads();
        int wid = t >> 6, lane = t & 63;
        int m = lane & 15, q = lane >> 4;
        int mbase = blockIdx.x * 128 + wid * 32;
        bool active = mbase < NN;
        float s8[8] = {0, 0, 0, 0, 0, 0, 0, 0};
        float ss8[8] = {0, 0, 0, 0, 0, 0, 0, 0};
        if (active) {
            int row0 = mbase + m;
            int row1 = min(mbase + 16 + m, NN - 1);
            const bf16x8* Abuf = (const bf16x8*)buf;
            const bf16x8* Ah = (const bf16x8*)h;
            size_t b0 = (size_t)row0 * 16, b1 = (size_t)row1 * 16;
            bf16x8 af0[8], af1[8];
#pragma unroll
            for (int kk = 0; kk < 4; ++kk) {
                af0[kk] = Abuf[b0 + kk * 4 + q];
                af1[kk] = Abuf[b1 + kk * 4 + q];
                bf16x8 h0 = Ah[b0 + kk * 4 + q];
                bf16x8 h1 = Ah[b1 + kk * 4 + q];
                int cb = kk * 32 + q * 8;
                h0 = norm8(h0, s_sc, s_sh, cb);
                h1 = norm8(h1, s_sc, s_sh, cb);
                af0[4 + kk] = h0;
                af1[4 + kk] = h1;
            }
            const bf16x8* B = (const bf16x8*)Bs;
            floatx4 acc[2][8];
#pragma unroll
            for (int mt = 0; mt < 2; ++mt)
#pragma unroll
                for (int nt = 0; nt < 8; ++nt) acc[mt][nt] = (floatx4){0.f, 0.f, 0.f, 0.f};
#pragma unroll
            for (int kk = 0; kk < 8; ++kk) {
#pragma unroll
                for (int nt = 0; nt < 8; ++nt) {
                    bf16x8 b = B[(nt * 8 + kk) * 64 + lane];
                    acc[0][nt] = __builtin_amdgcn_mfma_f32_16x16x32_bf16(af0[kk], b, acc[0][nt], 0, 0, 0);
                    acc[1][nt] = __builtin_amdgcn_mfma_f32_16x16x32_bf16(af1[kk], b, acc[1][nt], 0, 0, 0);
                }
            }
#pragma unroll
            for (int mt = 0; mt < 2; ++mt)
#pragma unroll
                for (int nt = 0; nt < 8; ++nt) {
                    int c = nt * 16 + m;
#pragma unroll
                    for (int reg = 0; reg < 4; ++reg) {
                        int r = mbase + mt * 16 + q * 4 + reg;
                        if (r < NN) {
                            float v = acc[mt][nt][reg];
                            sout[(size_t)r * 128 + c] = f2b(v);
                            s8[nt] += v;
                            ss8[nt] += v * v;
                        }
                    }
                }
#pragma unroll
            for (int nt = 0; nt < 8; ++nt) {
                s8[nt] += __shfl_xor(s8[nt], 16, 64);  s8[nt] += __shfl_xor(s8[nt], 32, 64);
                ss8[nt] += __shfl_xor(ss8[nt], 16, 64); ss8[nt] += __shfl_xor(ss8[nt], 32, 64);
            }
        }
        __syncthreads();
        float* stf = (float*)Bs;
        if (t < 256) stf[t] = 0.f;
        __syncthreads();
        if (active && (t & 63) < 16) {
#pragma unroll
            for (int nt = 0; nt < 8; ++nt) {
                int c = nt * 16 + (t & 15);
                atomicAdd(&stf[c], s8[nt]);
                atomicAdd(&stf[128 + c], ss8[nt]);
            }
        }
        __syncthreads();
        if (t < 256) atomicAdd(&sbnstat[t], stf[t]);
        __syncthreads();  // Bs reused next rep
    }
}

// p_hist: k_hist x PR_HIST into scratch deg
__global__ void p_hist(const int* __restrict__ dst, int* sdeg) {
    int bucket = blockIdx.x & (SC_NB - 1);
    int chunk = blockIdx.x / SC_NB;
    int lo = bucket * SC_BSZ, hi = lo + SC_BSZ;
    int base = chunk * SC_CHUNK;
#pragma unroll 1
    for (int rep = 0; rep < PR_HIST; ++rep) {
#pragma unroll
        for (int i = 0; i < SC_CHUNK / 256; ++i) {
            int e = base + i * 256 + threadIdx.x;
            if (e < NE) {
                int d = dst[e];
                if (d >= lo && d < hi) atomicAdd(&sdeg[d], 1);
            }
        }
    }
}

// p_scat: k_scatter x PR_SCAT with 3 pre-initialized scratch cursors
__global__ void p_scat(const int* __restrict__ src, const int* __restrict__ dst,
                       int* pc0, int* pc1, int* pc2, int* scol) {
    int bucket = blockIdx.x & (SC_NB - 1);
    int chunk = blockIdx.x / SC_NB;
    int lo = bucket * SC_BSZ, hi = lo + SC_BSZ;
    int base = chunk * SC_CHUNK;
    int* curs[3] = {pc0, pc1, pc2};
#pragma unroll 1
    for (int rep = 0; rep < PR_SCAT; ++rep) {
        int* cursor = curs[rep];
#pragma unroll
        for (int i = 0; i < SC_CHUNK / 256; ++i) {
            int e = base + i * 256 + threadIdx.x;
            if (e < NE) {
                int d = dst[e];
                if (d >= lo && d < hi) {
                    int p = atomicAdd(&cursor[d], 1);
                    scol[p] = src[e];
                }
            }
        }
    }
}

// ---------------- launch ----------------
extern "C" void kernel_launch(void* const* d_in, const int* in_sizes, int n_in,
                              void* d_out, int out_size, void* d_ws, size_t ws_size,
                              hipStream_t stream) {
    const float* x = (const float*)d_in[0];
    const int* ei = (const int*)d_in[1];
    const int* batch = (const int*)d_in[2];
    const float* gfeats = (const float*)d_in[3];
    const float *Wl[3], *Wr[3], *gma[3], *bta[3];
    for (int i = 0; i < 3; ++i) {
        Wl[i] = (const float*)d_in[4 + 5 * i];
        Wr[i] = (const float*)d_in[6 + 5 * i];
        gma[i] = (const float*)d_in[7 + 5 * i];
        bta[i] = (const float*)d_in[8 + 5 * i];
    }
    const float* W1 = (const float*)d_in[19];
    const float* bs1 = (const float*)d_in[20];
    const float* W2 = (const float*)d_in[21];
    const float* bs2 = (const float*)d_in[22];
    const float* W3 = (const float*)d_in[23];
    const float* bs3 = (const float*)d_in[24];

    char* p = (char*)d_ws;
    auto alloc = [&](size_t bytes) -> char* {
        char* r = p;
        p += (bytes + 255) & ~(size_t)255;
        return r;
    };
    int* deg = (int*)alloc(NN * 4);
    int* row_start = (int*)alloc((NN + 1) * 4);
    int* cursor = (int*)alloc(NN * 4);
    int* col = (int*)alloc(NE * 4);
    int* gstart = (int*)alloc(NG * 4);
    int* gend = (int*)alloc(NG * 4);
    float* bnstats = (float*)alloc(3 * 256 * 4);
    float* pool_sum = (float*)alloc(NG * HID * 4);
    int* pool_max = (int*)alloc(NG * HID * 4);
    int* blocksum = (int*)alloc(SCAN_BLOCKS * 4);
    unsigned short* Bp = (unsigned short*)alloc(3 * 32768 * 2);
    unsigned short* xb = (unsigned short*)alloc((size_t)NN * 128 * 2);
    unsigned short* b0 = (unsigned short*)alloc((size_t)NN * 128 * 2);
    unsigned short* b1 = (unsigned short*)alloc((size_t)NN * 128 * 2);
    // probe scratch
    unsigned short* s_h = (unsigned short*)alloc((size_t)NN * 128 * 2);
    float* s_bn = (float*)alloc(256 * 4);
    int* s_deg = (int*)alloc(NN * 4);
    int* s_col = (int*)alloc(NE * 4);
    int* pc0 = (int*)alloc(NN * 4);
    int* pc1 = (int*)alloc(NN * 4);
    int* pc2 = (int*)alloc(NN * 4);

    const int* srcv = ei;
    const int* dstv = ei + NE;

    k_setup<<<(NN * 64 + 255) / 256, 256, 0, stream>>>(
        x, xb, deg, gstart, gend, bnstats, pool_sum, pool_max,
        Wl[0], Wr[0], Wl[1], Wr[1], Wl[2], Wr[2], Bp);
    k_hist<<<SC_CHUNKS * SC_NB, 256, 0, stream>>>(dstv, deg);
    k_scan1<<<SCAN_BLOCKS, 256, 0, stream>>>(deg, blocksum, batch, gstart, gend);
    k_scan23<<<SCAN_BLOCKS, 256, 0, stream>>>(deg, blocksum, row_start, cursor,
                                              pc0, pc1, pc2);
    k_scatter<<<SC_CHUNKS * SC_NB, 256, 0, stream>>>(srcv, dstv, cursor, col);

    const unsigned short* hin = xb;
    unsigned short* work[3] = {b0, b1, b0};
    for (int l = 0; l < 3; ++l) {
        unsigned short* w = work[l];
        const float* pb = (l == 0) ? nullptr : bnstats + (l - 1) * 256;
        const float* pg = (l == 0) ? nullptr : gma[l - 1];
        const float* pt = (l == 0) ? nullptr : bta[l - 1];
        k_agg<<<(NN + 15) / 16, 256, 0, stream>>>(hin, row_start, col, pb, pg, pt, w);
        k_gemm<<<GEMM_BLOCKS, 256, 0, stream>>>(w, hin, Bp + l * 32768, pb, pg, pt,
                                                bnstats + l * 256);
        hin = w;
    }
    k_pool<<<NG * 8, 256, 0, stream>>>(hin, gstart, gend, bnstats + 2 * 256, gma[2], bta[2],
                                       pool_sum, pool_max);
    k_head<<<NG, 128, 0, stream>>>(pool_sum, pool_max, gstart, gend, gfeats,
                                   W1, bs1, W2, bs2, W3, bs3, (float*)d_out);

    // -------- probes (scratch-only; appended so production output is done) ----
    p_agg<<<(NN + 15) / 16, 256, 0, stream>>>(xb, row_start, col, bnstats, gma[0], bta[0], s_h);
    p_gemm<<<GEMM_BLOCKS, 256, 0, stream>>>(b1, xb, Bp, bnstats, gma[0], bta[0], s_bn, s_h);
    p_hist<<<SC_CHUNKS * SC_NB, 256, 0, stream>>>(dstv, s_deg);
    p_scat<<<SC_CHUNKS * SC_NB, 256, 0, stream>>>(srcv, dstv, pc0, pc1, pc2, s_col);
}

// Round 6
// 469.544 us; speedup vs baseline: 1.5939x; 1.5939x over previous
//
#include <hip/hip_runtime.h>
#include <stdint.h>

#define NN 50000
#define NE 800000
#define HID 128
#define NG 64
#define BN_EPS 1e-5f
#define GEMM_BLOCKS ((NN + 127) / 128)
#define SC_NB 8                                  // buckets (== XCD count)
#define SC_BSZ ((NN + SC_NB - 1) / SC_NB)        // 6250 nodes per bucket
#define SC_CHUNK 4096                            // edges per block
#define SC_CHUNKS ((NE + SC_CHUNK - 1) / SC_CHUNK)
#define CAP 96   // fixed CSR row capacity; Poisson(16) P(deg>96) ~ 1e-40
#define PR_AGG 4 // probe repeat count (one probe per round; must dominate top-5)

typedef __bf16 bf16x8 __attribute__((ext_vector_type(8)));
typedef float floatx4 __attribute__((ext_vector_type(4)));

__device__ __forceinline__ float b2f(unsigned short u) {
    union { unsigned int i; float f; } x; x.i = ((unsigned int)u) << 16; return x.f;
}
__device__ __forceinline__ float blo(unsigned int d) { return __uint_as_float(d << 16); }
__device__ __forceinline__ float bhi(unsigned int d) { return __uint_as_float(d & 0xffff0000u); }
__device__ __forceinline__ unsigned short f2b(float f) {
    union { float f; unsigned int i; } x; x.f = f; unsigned int i = x.i;
    if ((i & 0x7f800000u) == 0x7f800000u) return (unsigned short)(i >> 16); // inf/nan
    return (unsigned short)((i + 0x7fffu + ((i >> 16) & 1u)) >> 16);        // RNE
}
__device__ __forceinline__ unsigned int pack2(float f0, float f1) {
    return (((unsigned int)f2b(f1)) << 16) | f2b(f0);
}
// folded BN scale/shift for column c (from raw sums)
__device__ __forceinline__ float2 bn_pair(const float* __restrict__ bnstat,
                                          const float* __restrict__ gamma,
                                          const float* __restrict__ beta, int c) {
    float mu = bnstat[c] * (1.f / NN);
    float var = bnstat[128 + c] * (1.f / NN) - mu * mu;
    float s = gamma[c] * rsqrtf(var + BN_EPS);
    return make_float2(s, beta[c] - mu * s);
}

// ---------------- setup (incl. weight prep) ----------------
__global__ void k_setup(const float* __restrict__ x, unsigned short* xb, int* cnt,
                        int* gstart, int* gend, float* bnstats,
                        float* pool_sum, int* pool_max,
                        const float* __restrict__ Wl0, const float* __restrict__ Wr0,
                        const float* __restrict__ Wl1, const float* __restrict__ Wr1,
                        const float* __restrict__ Wl2, const float* __restrict__ Wr2,
                        unsigned short* Bp) {
    int i = blockIdx.x * 256 + threadIdx.x;
    if (i < NN * 64) {
        float2 v = ((const float2*)x)[i];
        ((unsigned int*)xb)[i] = pack2(v.x, v.y);
    }
    if (i < NN) cnt[i] = 0;
    if (i < NG) { gstart[i] = NN; gend[i] = -1; }  // empty-graph-safe defaults
    if (i < 3 * 256) bnstats[i] = 0.f;
    if (i < NG * HID) { pool_sum[i] = 0.f; pool_max[i] = 0; }
    if (i < 3 * 32768) {
        int layer = i >> 15;
        int r = i & 32767;
        int nt = r >> 12, kk = (r >> 9) & 7, l = (r >> 3) & 63, j = r & 7;
        int k = kk * 32 + (l >> 4) * 8 + j;
        int n = nt * 16 + (l & 15);
        const float* Wl = layer == 0 ? Wl0 : (layer == 1 ? Wl1 : Wl2);
        const float* Wr = layer == 0 ? Wr0 : (layer == 1 ? Wr1 : Wr2);
        Bp[i] = f2b((k < 128) ? Wl[k * 128 + n] : Wr[(k - 128) * 128 + n]);
    }
}

// graph bounds (separate dispatch after setup: no race with the defaults init;
// each boundary is written by exactly one thread; launch overhead ~0 per R4)
__global__ void k_bounds(const int* __restrict__ batch, int* gstart, int* gend) {
    int i = blockIdx.x * 256 + threadIdx.x;
    if (i < NN) {
        int g = batch[i];
        if (i == 0 || batch[i - 1] != g) gstart[g] = i;
        if (i == NN - 1 || batch[i + 1] != g) gend[g] = i;
    }
}

// XCD-bucketized scatter into fixed-capacity CSR. No hist/scan/cursor needed:
// pos = atomicAdd(cnt[d]); col writes for one bucket stay in one XCD L2 slice
// (6250*384B = 2.4MB). Replaces k_hist (~35us, atomic-bound per R5 probe) +
// k_scan1 + k_scan23 entirely.
__global__ void k_scatter(const int* __restrict__ src, const int* __restrict__ dst,
                          int* cnt, int* col) {
    int bucket = blockIdx.x & (SC_NB - 1);
    int chunk = blockIdx.x / SC_NB;
    int lo = bucket * SC_BSZ, hi = lo + SC_BSZ;
    int base = chunk * SC_CHUNK;
#pragma unroll
    for (int i = 0; i < SC_CHUNK / 256; ++i) {
        int e = base + i * 256 + threadIdx.x;
        if (e < NE) {
            int d = dst[e];
            if (d >= lo && d < hi) {
                int p = atomicAdd(&cnt[d], 1);
                if (p < CAP) col[d * CAP + p] = src[e];
            }
        }
    }
}

// ---------------- per-layer kernels ----------------
// mean aggregation over post-norm values computed on the fly; 16 lanes per node
// (sub = 16B chunk of the 256B row), 4 nodes per wave; wave-cooperative row
// reads are fully coalesced and col[] is broadcast across each 16-lane group.
__global__ void k_agg(const unsigned short* __restrict__ h, const int* __restrict__ cnt,
                      const int* __restrict__ col, const float* __restrict__ bnstat,
                      const float* __restrict__ gamma, const float* __restrict__ beta,
                      unsigned short* __restrict__ agg) {
    int wid = threadIdx.x >> 6, lane = threadIdx.x & 63;
    int slot = lane >> 4, sub = lane & 15;
    int node = (blockIdx.x * 4 + wid) * 4 + slot;  // 3125*4*4 == 50000 exactly
    int n = cnt[node]; if (n > CAP) n = CAP;
    const int* row = col + node * CAP;
    bool ap = bnstat != nullptr;
    float scv[8], shv[8];
    if (ap) {
#pragma unroll
        for (int i = 0; i < 8; ++i) {
            float2 p = bn_pair(bnstat, gamma, beta, sub * 8 + i);
            scv[i] = p.x; shv[i] = p.y;
        }
    }
    auto tf = [&](float f, int i) -> float {
        return ap ? fmaxf(f * scv[i] + shv[i], 0.f) : f;
    };
    const uint4* h4 = (const uint4*)h;  // one row = 16 uint4 (256B)
    float a0 = 0.f, a1 = 0.f, a2 = 0.f, a3 = 0.f, a4 = 0.f, a5 = 0.f, a6 = 0.f, a7 = 0.f;
    int j = 0;
    for (; j + 4 <= n; j += 4) {
        int u0 = row[j], u1 = row[j + 1], u2 = row[j + 2], u3 = row[j + 3];
        uint4 v0 = h4[(size_t)u0 * 16 + sub];
        uint4 v1 = h4[(size_t)u1 * 16 + sub];
        uint4 v2 = h4[(size_t)u2 * 16 + sub];
        uint4 v3 = h4[(size_t)u3 * 16 + sub];
        a0 += (tf(blo(v0.x), 0) + tf(blo(v1.x), 0)) + (tf(blo(v2.x), 0) + tf(blo(v3.x), 0));
        a1 += (tf(bhi(v0.x), 1) + tf(bhi(v1.x), 1)) + (tf(bhi(v2.x), 1) + tf(bhi(v3.x), 1));
        a2 += (tf(blo(v0.y), 2) + tf(blo(v1.y), 2)) + (tf(blo(v2.y), 2) + tf(blo(v3.y), 2));
        a3 += (tf(bhi(v0.y), 3) + tf(bhi(v1.y), 3)) + (tf(bhi(v2.y), 3) + tf(bhi(v3.y), 3));
        a4 += (tf(blo(v0.z), 4) + tf(blo(v1.z), 4)) + (tf(blo(v2.z), 4) + tf(blo(v3.z), 4));
        a5 += (tf(bhi(v0.z), 5) + tf(bhi(v1.z), 5)) + (tf(bhi(v2.z), 5) + tf(bhi(v3.z), 5));
        a6 += (tf(blo(v0.w), 6) + tf(blo(v1.w), 6)) + (tf(blo(v2.w), 6) + tf(blo(v3.w), 6));
        a7 += (tf(bhi(v0.w), 7) + tf(bhi(v1.w), 7)) + (tf(bhi(v2.w), 7) + tf(bhi(v3.w), 7));
    }
    for (; j < n; ++j) {
        int u = row[j];
        uint4 v = h4[(size_t)u * 16 + sub];
        a0 += tf(blo(v.x), 0);  a1 += tf(bhi(v.x), 1);
        a2 += tf(blo(v.y), 2);  a3 += tf(bhi(v.y), 3);
        a4 += tf(blo(v.z), 4);  a5 += tf(bhi(v.z), 5);
        a6 += tf(blo(v.w), 6);  a7 += tf(bhi(v.w), 7);
    }
    float inv = (n > 0) ? 1.f / (float)n : 0.f;
    uint4 o;
    o.x = pack2(a0 * inv, a1 * inv);
    o.y = pack2(a2 * inv, a3 * inv);
    o.z = pack2(a4 * inv, a5 * inv);
    o.w = pack2(a6 * inv, a7 * inv);
    ((uint4*)agg)[(size_t)node * 16 + sub] = o;
}

// apply folded norm (from LDS tables) to a bf16x8 fragment (cols cbase..cbase+7)
__device__ __forceinline__ bf16x8 norm8(bf16x8 v, const float* sc, const float* sh, int cbase) {
    union { bf16x8 v; unsigned short u[8]; } in; in.v = v;
    union { unsigned int u[4]; bf16x8 v; } out;
#pragma unroll
    for (int i = 0; i < 4; ++i) {
        float f0 = fmaxf(b2f(in.u[2 * i]) * sc[cbase + 2 * i] + sh[cbase + 2 * i], 0.f);
        float f1 = fmaxf(b2f(in.u[2 * i + 1]) * sc[cbase + 2 * i + 1] + sh[cbase + 2 * i + 1], 0.f);
        out.u[i] = pack2(f0, f1);
    }
    return out.v;
}

// buf[M,128] <- [buf | norm(h)][M,256] @ Wcat[256,128], bf16 in-place
__global__ void __launch_bounds__(256) k_gemm(unsigned short* buf,
                                              const unsigned short* h,
                                              const unsigned short* __restrict__ Bp,
                                              const float* __restrict__ pbnstat,
                                              const float* __restrict__ pgamma,
                                              const float* __restrict__ pbeta,
                                              float* bnstat) {
    __shared__ unsigned short Bs[32768];  // 64KB B fragments; reused for stat reduce
    __shared__ float s_sc[128], s_sh[128];
    int t = threadIdx.x;
    {
        const uint4* s4 = (const uint4*)Bp;
        uint4* d4 = (uint4*)Bs;
        for (int i = t; i < 4096; i += 256) d4[i] = s4[i];
    }
    bool ap = pbnstat != nullptr;
    if (ap && t < 128) {
        float2 p = bn_pair(pbnstat, pgamma, pbeta, t);
        s_sc[t] = p.x; s_sh[t] = p.y;
    }
    __syncthreads();
    int wid = t >> 6, lane = t & 63;
    int m = lane & 15, q = lane >> 4;
    int mbase = blockIdx.x * 128 + wid * 32;
    bool active = mbase < NN;
    float s8[8] = {0, 0, 0, 0, 0, 0, 0, 0};
    float ss8[8] = {0, 0, 0, 0, 0, 0, 0, 0};
    if (active) {
        int row0 = mbase + m;
        int row1 = min(mbase + 16 + m, NN - 1);  // clamp tail (stores masked below)
        const bf16x8* Abuf = (const bf16x8*)buf;
        const bf16x8* Ah = (const bf16x8*)h;
        size_t b0 = (size_t)row0 * 16, b1 = (size_t)row1 * 16;
        bf16x8 af0[8], af1[8];
#pragma unroll
        for (int kk = 0; kk < 4; ++kk) {
            af0[kk] = Abuf[b0 + kk * 4 + q];
            af1[kk] = Abuf[b1 + kk * 4 + q];
            bf16x8 h0 = Ah[b0 + kk * 4 + q];
            bf16x8 h1 = Ah[b1 + kk * 4 + q];
            if (ap) {
                int cb = kk * 32 + q * 8;
                h0 = norm8(h0, s_sc, s_sh, cb);
                h1 = norm8(h1, s_sc, s_sh, cb);
            }
            af0[4 + kk] = h0;
            af1[4 + kk] = h1;
        }
        const bf16x8* B = (const bf16x8*)Bs;
        floatx4 acc[2][8];
#pragma unroll
        for (int mt = 0; mt < 2; ++mt)
#pragma unroll
            for (int nt = 0; nt < 8; ++nt) acc[mt][nt] = (floatx4){0.f, 0.f, 0.f, 0.f};
#pragma unroll
        for (int kk = 0; kk < 8; ++kk) {
#pragma unroll
            for (int nt = 0; nt < 8; ++nt) {
                bf16x8 b = B[(nt * 8 + kk) * 64 + lane];
                acc[0][nt] = __builtin_amdgcn_mfma_f32_16x16x32_bf16(af0[kk], b, acc[0][nt], 0, 0, 0);
                acc[1][nt] = __builtin_amdgcn_mfma_f32_16x16x32_bf16(af1[kk], b, acc[1][nt], 0, 0, 0);
            }
        }
#pragma unroll
        for (int mt = 0; mt < 2; ++mt)
#pragma unroll
            for (int nt = 0; nt < 8; ++nt) {
                int c = nt * 16 + m;  // C/D: col = lane&15
#pragma unroll
                for (int reg = 0; reg < 4; ++reg) {
                    int r = mbase + mt * 16 + q * 4 + reg;  // C/D: row = quad*4+reg
                    if (r < NN) {
                        float v = acc[mt][nt][reg];
                        buf[(size_t)r * 128 + c] = f2b(v);
                        s8[nt] += v;
                        ss8[nt] += v * v;
                    }
                }
            }
#pragma unroll
        for (int nt = 0; nt < 8; ++nt) {
            s8[nt] += __shfl_xor(s8[nt], 16, 64);  s8[nt] += __shfl_xor(s8[nt], 32, 64);
            ss8[nt] += __shfl_xor(ss8[nt], 16, 64); ss8[nt] += __shfl_xor(ss8[nt], 32, 64);
        }
    }
    __syncthreads();  // all waves done reading Bs
    float* stf = (float*)Bs;
    if (t < 256) stf[t] = 0.f;
    __syncthreads();
    if (active && lane < 16) {
#pragma unroll
        for (int nt = 0; nt < 8; ++nt) {
            int c = nt * 16 + m;
            atomicAdd(&stf[c], s8[nt]);
            atomicAdd(&stf[128 + c], ss8[nt]);
        }
    }
    __syncthreads();
    if (t < 256) atomicAdd(&bnstat[t], stf[t]);
}

// ---------------- pooling (folded norm inline) + head ----------------
__global__ void k_pool(const unsigned short* __restrict__ h, const int* __restrict__ gstart,
                       const int* __restrict__ gend, const float* __restrict__ bnstat,
                       const float* __restrict__ gamma, const float* __restrict__ beta,
                       float* pool_sum, int* pool_max) {
    int g = blockIdx.x >> 3, chunk = blockIdx.x & 7;
    int s = gstart[g], e = gend[g];
    if (s > e) return;
    int cnt = e - s + 1;
    int per = (cnt + 7) >> 3;
    int r0 = s + chunk * per;
    int r1 = min(r0 + per, e + 1);
    int c = threadIdx.x & 127, half = threadIdx.x >> 7;
    float2 pr = bn_pair(bnstat, gamma, beta, c);
    float sm = 0.f, mx = 0.f;  // post-relu values are >= 0
    for (int r = r0 + half; r < r1; r += 2) {
        float v = fmaxf(b2f(h[(size_t)r * 128 + c]) * pr.x + pr.y, 0.f);
        sm += v;
        mx = fmaxf(mx, v);
    }
    atomicAdd(&pool_sum[g * 128 + c], sm);
    atomicMax(&pool_max[g * 128 + c], __float_as_int(mx));  // valid for >=0 floats
}

__global__ void __launch_bounds__(128) k_head(
    const float* __restrict__ pool_sum, const int* __restrict__ pool_max,
    const int* __restrict__ gstart, const int* __restrict__ gend,
    const float* __restrict__ gfeats,
    const float* __restrict__ W1, const float* __restrict__ bs1,
    const float* __restrict__ W2, const float* __restrict__ bs2,
    const float* __restrict__ W3, const float* __restrict__ bs3,
    float* out) {
    __shared__ float m[288];
    __shared__ float o1[128];
    __shared__ float o2[64];
    int g = blockIdx.x, t = threadIdx.x;
    int s = gstart[g], e = gend[g];
    int cint = e - s + 1;
    float cnt = (float)(cint < 1 ? 1 : cint);
    if (t < 128) {
        m[t] = pool_sum[g * 128 + t] / cnt;
        m[128 + t] = __int_as_float(pool_max[g * 128 + t]);
    }
    if (t < 32) m[256 + t] = gfeats[g * 32 + t];
    __syncthreads();
    float acc = bs1[t];
    for (int k = 0; k < 288; ++k) acc += m[k] * W1[k * 128 + t];
    o1[t] = fmaxf(acc, 0.f);
    __syncthreads();
    if (t < 64) {
        float a2 = bs2[t];
        for (int k = 0; k < 128; ++k) a2 += o1[k] * W2[k * 64 + t];
        o2[t] = fmaxf(a2, 0.f);
    }
    __syncthreads();
    if (t < 64) {
        float p = o2[t] * W3[t];
#pragma unroll
        for (int off = 32; off; off >>= 1) p += __shfl_down(p, off, 64);
        if (t == 0) out[g] = p + bs3[0];
    }
}

// ================= PROBE (scratch-only; one per round — top-5 shows only the
// largest kernel). p_agg = k_agg body x PR_AGG; t_agg = dur/PR_AGG. ===========
__global__ void p_agg(const unsigned short* h, const int* cnt,
                      const int* col, const float* bnstat,
                      const float* gamma, const float* beta,
                      unsigned short* scratch) {
    int wid = threadIdx.x >> 6, lane = threadIdx.x & 63;
    int slot = lane >> 4, sub = lane & 15;
    int node = (blockIdx.x * 4 + wid) * 4 + slot;
    int n = cnt[node]; if (n > CAP) n = CAP;
    const int* row = col + node * CAP;
    float scv[8], shv[8];
#pragma unroll
    for (int i = 0; i < 8; ++i) {
        float2 p = bn_pair(bnstat, gamma, beta, sub * 8 + i);
        scv[i] = p.x; shv[i] = p.y;
    }
    auto tf = [&](float f, int i) -> float { return fmaxf(f * scv[i] + shv[i], 0.f); };
    const uint4* h4 = (const uint4*)h;
#pragma unroll 1
    for (int rep = 0; rep < PR_AGG; ++rep) {
        float a0 = 0.f, a1 = 0.f, a2 = 0.f, a3 = 0.f, a4 = 0.f, a5 = 0.f, a6 = 0.f, a7 = 0.f;
        int j = 0;
        for (; j + 4 <= n; j += 4) {
            int u0 = row[j], u1 = row[j + 1], u2 = row[j + 2], u3 = row[j + 3];
            uint4 v0 = h4[(size_t)u0 * 16 + sub];
            uint4 v1 = h4[(size_t)u1 * 16 + sub];
            uint4 v2 = h4[(size_t)u2 * 16 + sub];
            uint4 v3 = h4[(size_t)u3 * 16 + sub];
            a0 += (tf(blo(v0.x), 0) + tf(blo(v1.x), 0)) + (tf(blo(v2.x), 0) + tf(blo(v3.x), 0));
            a1 += (tf(bhi(v0.x), 1) + tf(bhi(v1.x), 1)) + (tf(bhi(v2.x), 1) + tf(bhi(v3.x), 1));
            a2 += (tf(blo(v0.y), 2) + tf(blo(v1.y), 2)) + (tf(blo(v2.y), 2) + tf(blo(v3.y), 2));
            a3 += (tf(bhi(v0.y), 3) + tf(bhi(v1.y), 3)) + (tf(bhi(v2.y), 3) + tf(bhi(v3.y), 3));
            a4 += (tf(blo(v0.z), 4) + tf(blo(v1.z), 4)) + (tf(blo(v2.z), 4) + tf(blo(v3.z), 4));
            a5 += (tf(bhi(v0.z), 5) + tf(bhi(v1.z), 5)) + (tf(bhi(v2.z), 5) + tf(bhi(v3.z), 5));
            a6 += (tf(blo(v0.w), 6) + tf(blo(v1.w), 6)) + (tf(blo(v2.w), 6) + tf(blo(v3.w), 6));
            a7 += (tf(bhi(v0.w), 7) + tf(bhi(v1.w), 7)) + (tf(bhi(v2.w), 7) + tf(bhi(v3.w), 7));
        }
        for (; j < n; ++j) {
            int u = row[j];
            uint4 v = h4[(size_t)u * 16 + sub];
            a0 += tf(blo(v.x), 0);  a1 += tf(bhi(v.x), 1);
            a2 += tf(blo(v.y), 2);  a3 += tf(bhi(v.y), 3);
            a4 += tf(blo(v.z), 4);  a5 += tf(bhi(v.z), 5);
            a6 += tf(blo(v.w), 6);  a7 += tf(bhi(v.w), 7);
        }
        float inv = (n > 0) ? 1.f / (float)n : 0.f;
        uint4 o;
        o.x = pack2(a0 * inv, a1 * inv);
        o.y = pack2(a2 * inv, a3 * inv);
        o.z = pack2(a4 * inv, a5 * inv);
        o.w = pack2(a6 * inv, a7 * inv);
        ((uint4*)scratch)[(size_t)node * 16 + sub] = o;
    }
}

// ---------------- launch ----------------
extern "C" void kernel_launch(void* const* d_in, const int* in_sizes, int n_in,
                              void* d_out, int out_size, void* d_ws, size_t ws_size,
                              hipStream_t stream) {
    const float* x = (const float*)d_in[0];
    const int* ei = (const int*)d_in[1];
    const int* batch = (const int*)d_in[2];
    const float* gfeats = (const float*)d_in[3];
    const float *Wl[3], *Wr[3], *gma[3], *bta[3];
    for (int i = 0; i < 3; ++i) {
        Wl[i] = (const float*)d_in[4 + 5 * i];
        // d_in[5+5i] = bl (cancelled by BatchNorm; unused)
        Wr[i] = (const float*)d_in[6 + 5 * i];
        gma[i] = (const float*)d_in[7 + 5 * i];
        bta[i] = (const float*)d_in[8 + 5 * i];
    }
    const float* W1 = (const float*)d_in[19];
    const float* bs1 = (const float*)d_in[20];
    const float* W2 = (const float*)d_in[21];
    const float* bs2 = (const float*)d_in[22];
    const float* W3 = (const float*)d_in[23];
    const float* bs3 = (const float*)d_in[24];

    char* p = (char*)d_ws;
    auto alloc = [&](size_t bytes) -> char* {
        char* r = p;
        p += (bytes + 255) & ~(size_t)255;
        return r;
    };
    int* cnt = (int*)alloc(NN * 4);
    int* col = (int*)alloc((size_t)NN * CAP * 4);
    int* gstart = (int*)alloc(NG * 4);
    int* gend = (int*)alloc(NG * 4);
    float* bnstats = (float*)alloc(3 * 256 * 4);
    float* pool_sum = (float*)alloc(NG * HID * 4);
    int* pool_max = (int*)alloc(NG * HID * 4);
    unsigned short* Bp = (unsigned short*)alloc(3 * 32768 * 2);
    unsigned short* xb = (unsigned short*)alloc((size_t)NN * 128 * 2);
    unsigned short* b0 = (unsigned short*)alloc((size_t)NN * 128 * 2);
    unsigned short* b1 = (unsigned short*)alloc((size_t)NN * 128 * 2);
    unsigned short* s_h = (unsigned short*)alloc((size_t)NN * 128 * 2);  // probe scratch

    const int* srcv = ei;
    const int* dstv = ei + NE;

    k_setup<<<(NN * 64 + 255) / 256, 256, 0, stream>>>(
        x, xb, cnt, gstart, gend, bnstats, pool_sum, pool_max,
        Wl[0], Wr[0], Wl[1], Wr[1], Wl[2], Wr[2], Bp);
    k_bounds<<<(NN + 255) / 256, 256, 0, stream>>>(batch, gstart, gend);
    k_scatter<<<SC_CHUNKS * SC_NB, 256, 0, stream>>>(srcv, dstv, cnt, col);

    // layer chain: hin (pre-BN of prev layer, or xb) -> w (pre-BN of this layer)
    const unsigned short* hin = xb;
    unsigned short* work[3] = {b0, b1, b0};
    for (int l = 0; l < 3; ++l) {
        unsigned short* w = work[l];
        const float* pb = (l == 0) ? nullptr : bnstats + (l - 1) * 256;
        const float* pg = (l == 0) ? nullptr : gma[l - 1];
        const float* pt = (l == 0) ? nullptr : bta[l - 1];
        k_agg<<<(NN + 15) / 16, 256, 0, stream>>>(hin, cnt, col, pb, pg, pt, w);
        k_gemm<<<GEMM_BLOCKS, 256, 0, stream>>>(w, hin, Bp + l * 32768, pb, pg, pt,
                                                bnstats + l * 256);
        hin = w;
    }
    k_pool<<<NG * 8, 256, 0, stream>>>(hin, gstart, gend, bnstats + 2 * 256, gma[2], bta[2],
                                       pool_sum, pool_max);
    k_head<<<NG, 128, 0, stream>>>(pool_sum, pool_max, gstart, gend, gfeats,
                                   W1, bs1, W2, bs2, W3, bs3, (float*)d_out);

    // -------- probe (scratch-only, after production output) --------
    p_agg<<<(NN + 15) / 16, 256, 0, stream>>>(xb, cnt, col, bnstats, gma[0], bta[0], s_h);
}

// Round 7
// 442.239 us; speedup vs baseline: 1.6923x; 1.0617x over previous
//
#include <hip/hip_runtime.h>
#include <stdint.h>

#define NN 50000
#define NE 800000
#define HID 128
#define NG 64
#define BN_EPS 1e-5f
#define GEMM_BLOCKS ((NN + 127) / 128)
#define SC_NB 8                                  // buckets (== XCD count)
#define SC_BSZ ((NN + SC_NB - 1) / SC_NB)        // 6250 nodes per bucket
#define SC_CHUNK 4096                            // edges per block
#define SC_CHUNKS ((NE + SC_CHUNK - 1) / SC_CHUNK)
#define CAP 96    // fixed CSR row capacity; Poisson(16) P(deg>96) ~ 1e-40
#define PR_GEMM 6 // probe repeat count (one probe per round; must cross ~44us)

typedef __bf16 bf16x8 __attribute__((ext_vector_type(8)));
typedef float floatx4 __attribute__((ext_vector_type(4)));

__device__ __forceinline__ float b2f(unsigned short u) {
    union { unsigned int i; float f; } x; x.i = ((unsigned int)u) << 16; return x.f;
}
__device__ __forceinline__ float blo(unsigned int d) { return __uint_as_float(d << 16); }
__device__ __forceinline__ float bhi(unsigned int d) { return __uint_as_float(d & 0xffff0000u); }
__device__ __forceinline__ unsigned short f2b(float f) {
    union { float f; unsigned int i; } x; x.f = f; unsigned int i = x.i;
    if ((i & 0x7f800000u) == 0x7f800000u) return (unsigned short)(i >> 16); // inf/nan
    return (unsigned short)((i + 0x7fffu + ((i >> 16) & 1u)) >> 16);        // RNE
}
__device__ __forceinline__ unsigned int pack2(float f0, float f1) {
    return (((unsigned int)f2b(f1)) << 16) | f2b(f0);
}
// folded BN scale/shift for column c (from raw sums)
__device__ __forceinline__ float2 bn_pair(const float* __restrict__ bnstat,
                                          const float* __restrict__ gamma,
                                          const float* __restrict__ beta, int c) {
    float mu = bnstat[c] * (1.f / NN);
    float var = bnstat[128 + c] * (1.f / NN) - mu * mu;
    float s = gamma[c] * rsqrtf(var + BN_EPS);
    return make_float2(s, beta[c] - mu * s);
}

// ---------------- setup (incl. weight prep) ----------------
__global__ void k_setup(const float* __restrict__ x, unsigned short* xb, int* cnt,
                        int* gstart, int* gend, float* bnstats,
                        float* pool_sum, int* pool_max,
                        const float* __restrict__ Wl0, const float* __restrict__ Wr0,
                        const float* __restrict__ Wl1, const float* __restrict__ Wr1,
                        const float* __restrict__ Wl2, const float* __restrict__ Wr2,
                        unsigned short* Bp) {
    int i = blockIdx.x * 256 + threadIdx.x;
    if (i < NN * 64) {
        float2 v = ((const float2*)x)[i];
        ((unsigned int*)xb)[i] = pack2(v.x, v.y);
    }
    if (i < NN) cnt[i] = 0;
    if (i < NG) { gstart[i] = NN; gend[i] = -1; }  // empty-graph-safe defaults
    if (i < 3 * 256) bnstats[i] = 0.f;
    if (i < NG * HID) { pool_sum[i] = 0.f; pool_max[i] = 0; }
    if (i < 3 * 32768) {
        int layer = i >> 15;
        int r = i & 32767;
        int nt = r >> 12, kk = (r >> 9) & 7, l = (r >> 3) & 63, j = r & 7;
        int k = kk * 32 + (l >> 4) * 8 + j;
        int n = nt * 16 + (l & 15);
        const float* Wl = layer == 0 ? Wl0 : (layer == 1 ? Wl1 : Wl2);
        const float* Wr = layer == 0 ? Wr0 : (layer == 1 ? Wr1 : Wr2);
        Bp[i] = f2b((k < 128) ? Wl[k * 128 + n] : Wr[(k - 128) * 128 + n]);
    }
}

// graph bounds (each boundary written by exactly one thread)
__global__ void k_bounds(const int* __restrict__ batch, int* gstart, int* gend) {
    int i = blockIdx.x * 256 + threadIdx.x;
    if (i < NN) {
        int g = batch[i];
        if (i == 0 || batch[i - 1] != g) gstart[g] = i;
        if (i == NN - 1 || batch[i + 1] != g) gend[g] = i;
    }
}

// XCD-bucketized scatter into fixed-capacity CSR (no hist/scan needed)
__global__ void k_scatter(const int* __restrict__ src, const int* __restrict__ dst,
                          int* cnt, int* col) {
    int bucket = blockIdx.x & (SC_NB - 1);
    int chunk = blockIdx.x / SC_NB;
    int lo = bucket * SC_BSZ, hi = lo + SC_BSZ;
    int base = chunk * SC_CHUNK;
#pragma unroll
    for (int i = 0; i < SC_CHUNK / 256; ++i) {
        int e = base + i * 256 + threadIdx.x;
        if (e < NE) {
            int d = dst[e];
            if (d >= lo && d < hi) {
                int p = atomicAdd(&cnt[d], 1);
                if (p < CAP) col[d * CAP + p] = src[e];
            }
        }
    }
}

// ---------------- per-layer kernels ----------------
// Raw mean aggregation (R6 probe: old agg was VALU-bound at 60% from per-edge
// BN+relu; norm is now pre-materialized per NODE by k_norm, so the inner loop
// is unpack+add only). 16 lanes per node (sub = 16B chunk of the 256B row),
// 4 nodes per wave; rows coalesced, col[] broadcast per 16-lane group.
__global__ void k_agg(const unsigned short* __restrict__ h, const int* __restrict__ cnt,
                      const int* __restrict__ col, unsigned short* __restrict__ agg) {
    int wid = threadIdx.x >> 6, lane = threadIdx.x & 63;
    int slot = lane >> 4, sub = lane & 15;
    int node = (blockIdx.x * 4 + wid) * 4 + slot;  // 3125*4*4 == 50000 exactly
    int n = cnt[node]; if (n > CAP) n = CAP;
    const int* row = col + node * CAP;
    const uint4* h4 = (const uint4*)h;  // one row = 16 uint4 (256B)
    float a0 = 0.f, a1 = 0.f, a2 = 0.f, a3 = 0.f, a4 = 0.f, a5 = 0.f, a6 = 0.f, a7 = 0.f;
    int j = 0;
    for (; j + 4 <= n; j += 4) {
        int u0 = row[j], u1 = row[j + 1], u2 = row[j + 2], u3 = row[j + 3];
        uint4 v0 = h4[(size_t)u0 * 16 + sub];
        uint4 v1 = h4[(size_t)u1 * 16 + sub];
        uint4 v2 = h4[(size_t)u2 * 16 + sub];
        uint4 v3 = h4[(size_t)u3 * 16 + sub];
        a0 += (blo(v0.x) + blo(v1.x)) + (blo(v2.x) + blo(v3.x));
        a1 += (bhi(v0.x) + bhi(v1.x)) + (bhi(v2.x) + bhi(v3.x));
        a2 += (blo(v0.y) + blo(v1.y)) + (blo(v2.y) + blo(v3.y));
        a3 += (bhi(v0.y) + bhi(v1.y)) + (bhi(v2.y) + bhi(v3.y));
        a4 += (blo(v0.z) + blo(v1.z)) + (blo(v2.z) + blo(v3.z));
        a5 += (bhi(v0.z) + bhi(v1.z)) + (bhi(v2.z) + bhi(v3.z));
        a6 += (blo(v0.w) + blo(v1.w)) + (blo(v2.w) + blo(v3.w));
        a7 += (bhi(v0.w) + bhi(v1.w)) + (bhi(v2.w) + bhi(v3.w));
    }
    for (; j < n; ++j) {
        int u = row[j];
        uint4 v = h4[(size_t)u * 16 + sub];
        a0 += blo(v.x);  a1 += bhi(v.x);
        a2 += blo(v.y);  a3 += bhi(v.y);
        a4 += blo(v.z);  a5 += bhi(v.z);
        a6 += blo(v.w);  a7 += bhi(v.w);
    }
    float inv = (n > 0) ? 1.f / (float)n : 0.f;
    uint4 o;
    o.x = pack2(a0 * inv, a1 * inv);
    o.y = pack2(a2 * inv, a3 * inv);
    o.z = pack2(a4 * inv, a5 * inv);
    o.w = pack2(a6 * inv, a7 * inv);
    ((uint4*)agg)[(size_t)node * 16 + sub] = o;
}

// materialize hn = relu(norm(pre)) once per node-value (memory-bound, ~26MB).
// Moves the BN+relu transform from per-EDGE (102M) to per-NODE (6.4M).
__global__ void k_norm(const unsigned short* __restrict__ pre,
                       const float* __restrict__ bnstat, const float* __restrict__ gamma,
                       const float* __restrict__ beta, unsigned short* __restrict__ hn) {
    __shared__ float sc[128], sh[128];
    int t = threadIdx.x;
    if (t < 128) {
        float2 p = bn_pair(bnstat, gamma, beta, t);
        sc[t] = p.x; sh[t] = p.y;
    }
    __syncthreads();
    int i = blockIdx.x * 256 + t;  // uint4 index; 3125*256 == NN*16 exactly
    uint4 v = ((const uint4*)pre)[i];
    int cb = (i & 15) * 8;
    uint4 o;
    o.x = pack2(fmaxf(blo(v.x) * sc[cb + 0] + sh[cb + 0], 0.f),
                fmaxf(bhi(v.x) * sc[cb + 1] + sh[cb + 1], 0.f));
    o.y = pack2(fmaxf(blo(v.y) * sc[cb + 2] + sh[cb + 2], 0.f),
                fmaxf(bhi(v.y) * sc[cb + 3] + sh[cb + 3], 0.f));
    o.z = pack2(fmaxf(blo(v.z) * sc[cb + 4] + sh[cb + 4], 0.f),
                fmaxf(bhi(v.z) * sc[cb + 5] + sh[cb + 5], 0.f));
    o.w = pack2(fmaxf(blo(v.w) * sc[cb + 6] + sh[cb + 6], 0.f),
                fmaxf(bhi(v.w) * sc[cb + 7] + sh[cb + 7], 0.f));
    ((uint4*)hn)[i] = o;
}

// buf[M,128] <- [buf | h][M,256] @ Wcat[256,128], bf16 in-place; BN stats of
// THIS layer accumulated. h is already post-norm (hn) or raw input (layer 0).
__global__ void __launch_bounds__(256) k_gemm(unsigned short* buf,
                                              const unsigned short* h,
                                              const unsigned short* __restrict__ Bp,
                                              float* bnstat) {
    __shared__ unsigned short Bs[32768];  // 64KB B fragments; reused for stat reduce
    int t = threadIdx.x;
    {
        const uint4* s4 = (const uint4*)Bp;
        uint4* d4 = (uint4*)Bs;
        for (int i = t; i < 4096; i += 256) d4[i] = s4[i];
    }
    __syncthreads();
    int wid = t >> 6, lane = t & 63;
    int m = lane & 15, q = lane >> 4;
    int mbase = blockIdx.x * 128 + wid * 32;
    bool active = mbase < NN;
    float s8[8] = {0, 0, 0, 0, 0, 0, 0, 0};
    float ss8[8] = {0, 0, 0, 0, 0, 0, 0, 0};
    if (active) {
        int row0 = mbase + m;
        int row1 = min(mbase + 16 + m, NN - 1);  // clamp tail (stores masked below)
        const bf16x8* Abuf = (const bf16x8*)buf;
        const bf16x8* Ah = (const bf16x8*)h;
        size_t b0 = (size_t)row0 * 16, b1 = (size_t)row1 * 16;
        bf16x8 af0[8], af1[8];
#pragma unroll
        for (int kk = 0; kk < 4; ++kk) {
            af0[kk] = Abuf[b0 + kk * 4 + q];
            af1[kk] = Abuf[b1 + kk * 4 + q];
            af0[4 + kk] = Ah[b0 + kk * 4 + q];
            af1[4 + kk] = Ah[b1 + kk * 4 + q];
        }
        const bf16x8* B = (const bf16x8*)Bs;
        floatx4 acc[2][8];
#pragma unroll
        for (int mt = 0; mt < 2; ++mt)
#pragma unroll
            for (int nt = 0; nt < 8; ++nt) acc[mt][nt] = (floatx4){0.f, 0.f, 0.f, 0.f};
#pragma unroll
        for (int kk = 0; kk < 8; ++kk) {
#pragma unroll
            for (int nt = 0; nt < 8; ++nt) {
                bf16x8 b = B[(nt * 8 + kk) * 64 + lane];
                acc[0][nt] = __builtin_amdgcn_mfma_f32_16x16x32_bf16(af0[kk], b, acc[0][nt], 0, 0, 0);
                acc[1][nt] = __builtin_amdgcn_mfma_f32_16x16x32_bf16(af1[kk], b, acc[1][nt], 0, 0, 0);
            }
        }
#pragma unroll
        for (int mt = 0; mt < 2; ++mt)
#pragma unroll
            for (int nt = 0; nt < 8; ++nt) {
                int c = nt * 16 + m;  // C/D: col = lane&15
#pragma unroll
                for (int reg = 0; reg < 4; ++reg) {
                    int r = mbase + mt * 16 + q * 4 + reg;  // C/D: row = quad*4+reg
                    if (r < NN) {
                        float v = acc[mt][nt][reg];
                        buf[(size_t)r * 128 + c] = f2b(v);
                        s8[nt] += v;
                        ss8[nt] += v * v;
                    }
                }
            }
#pragma unroll
        for (int nt = 0; nt < 8; ++nt) {
            s8[nt] += __shfl_xor(s8[nt], 16, 64);  s8[nt] += __shfl_xor(s8[nt], 32, 64);
            ss8[nt] += __shfl_xor(ss8[nt], 16, 64); ss8[nt] += __shfl_xor(ss8[nt], 32, 64);
        }
    }
    __syncthreads();  // all waves done reading Bs
    float* stf = (float*)Bs;
    if (t < 256) stf[t] = 0.f;
    __syncthreads();
    if (active && lane < 16) {
#pragma unroll
        for (int nt = 0; nt < 8; ++nt) {
            int c = nt * 16 + m;
            atomicAdd(&stf[c], s8[nt]);
            atomicAdd(&stf[128 + c], ss8[nt]);
        }
    }
    __syncthreads();
    if (t < 256) atomicAdd(&bnstat[t], stf[t]);
}

// ---------------- pooling (folded norm inline) + head ----------------
__global__ void k_pool(const unsigned short* __restrict__ h, const int* __restrict__ gstart,
                       const int* __restrict__ gend, const float* __restrict__ bnstat,
                       const float* __restrict__ gamma, const float* __restrict__ beta,
                       float* pool_sum, int* pool_max) {
    int g = blockIdx.x >> 3, chunk = blockIdx.x & 7;
    int s = gstart[g], e = gend[g];
    if (s > e) return;
    int cnt = e - s + 1;
    int per = (cnt + 7) >> 3;
    int r0 = s + chunk * per;
    int r1 = min(r0 + per, e + 1);
    int c = threadIdx.x & 127, half = threadIdx.x >> 7;
    float2 pr = bn_pair(bnstat, gamma, beta, c);
    float sm = 0.f, mx = 0.f;  // post-relu values are >= 0
    for (int r = r0 + half; r < r1; r += 2) {
        float v = fmaxf(b2f(h[(size_t)r * 128 + c]) * pr.x + pr.y, 0.f);
        sm += v;
        mx = fmaxf(mx, v);
    }
    atomicAdd(&pool_sum[g * 128 + c], sm);
    atomicMax(&pool_max[g * 128 + c], __float_as_int(mx));  // valid for >=0 floats
}

__global__ void __launch_bounds__(128) k_head(
    const float* __restrict__ pool_sum, const int* __restrict__ pool_max,
    const int* __restrict__ gstart, const int* __restrict__ gend,
    const float* __restrict__ gfeats,
    const float* __restrict__ W1, const float* __restrict__ bs1,
    const float* __restrict__ W2, const float* __restrict__ bs2,
    const float* __restrict__ W3, const float* __restrict__ bs3,
    float* out) {
    __shared__ float m[288];
    __shared__ float o1[128];
    __shared__ float o2[64];
    int g = blockIdx.x, t = threadIdx.x;
    int s = gstart[g], e = gend[g];
    int cint = e - s + 1;
    float cnt = (float)(cint < 1 ? 1 : cint);
    if (t < 128) {
        m[t] = pool_sum[g * 128 + t] / cnt;
        m[128 + t] = __int_as_float(pool_max[g * 128 + t]);
    }
    if (t < 32) m[256 + t] = gfeats[g * 32 + t];
    __syncthreads();
    float acc = bs1[t];
    for (int k = 0; k < 288; ++k) acc += m[k] * W1[k * 128 + t];
    o1[t] = fmaxf(acc, 0.f);
    __syncthreads();
    if (t < 64) {
        float a2 = bs2[t];
        for (int k = 0; k < 128; ++k) a2 += o1[k] * W2[k * 64 + t];
        o2[t] = fmaxf(a2, 0.f);
    }
    __syncthreads();
    if (t < 64) {
        float p = o2[t] * W3[t];
#pragma unroll
        for (int off = 32; off; off >>= 1) p += __shfl_down(p, off, 64);
        if (t == 0) out[g] = p + bs3[0];
    }
}

// ================= PROBE (scratch-only; one per round) =======================
// p_gemm = full k_gemm body x PR_GEMM (incl. LDS staging). t_gemm = dur/PR_GEMM.
__global__ void __launch_bounds__(256) p_gemm(unsigned short* buf,
                                              const unsigned short* h,
                                              const unsigned short* Bp,
                                              float* sbnstat) {
    __shared__ unsigned short Bs[32768];
    int t = threadIdx.x;
#pragma unroll 1
    for (int rep = 0; rep < PR_GEMM; ++rep) {
        {
            const uint4* s4 = (const uint4*)Bp;
            uint4* d4 = (uint4*)Bs;
            for (int i = t; i < 4096; i += 256) d4[i] = s4[i];
        }
        __syncthreads();
        int wid = t >> 6, lane = t & 63;
        int m = lane & 15, q = lane >> 4;
        int mbase = blockIdx.x * 128 + wid * 32;
        bool active = mbase < NN;
        float s8[8] = {0, 0, 0, 0, 0, 0, 0, 0};
        float ss8[8] = {0, 0, 0, 0, 0, 0, 0, 0};
        if (active) {
            int row0 = mbase + m;
            int row1 = min(mbase + 16 + m, NN - 1);
            const bf16x8* Abuf = (const bf16x8*)buf;
            const bf16x8* Ah = (const bf16x8*)h;
            size_t b0 = (size_t)row0 * 16, b1 = (size_t)row1 * 16;
            bf16x8 af0[8], af1[8];
#pragma unroll
            for (int kk = 0; kk < 4; ++kk) {
                af0[kk] = Abuf[b0 + kk * 4 + q];
                af1[kk] = Abuf[b1 + kk * 4 + q];
                af0[4 + kk] = Ah[b0 + kk * 4 + q];
                af1[4 + kk] = Ah[b1 + kk * 4 + q];
            }
            const bf16x8* B = (const bf16x8*)Bs;
            floatx4 acc[2][8];
#pragma unroll
            for (int mt = 0; mt < 2; ++mt)
#pragma unroll
                for (int nt = 0; nt < 8; ++nt) acc[mt][nt] = (floatx4){0.f, 0.f, 0.f, 0.f};
#pragma unroll
            for (int kk = 0; kk < 8; ++kk) {
#pragma unroll
                for (int nt = 0; nt < 8; ++nt) {
                    bf16x8 b = B[(nt * 8 + kk) * 64 + lane];
                    acc[0][nt] = __builtin_amdgcn_mfma_f32_16x16x32_bf16(af0[kk], b, acc[0][nt], 0, 0, 0);
                    acc[1][nt] = __builtin_amdgcn_mfma_f32_16x16x32_bf16(af1[kk], b, acc[1][nt], 0, 0, 0);
                }
            }
#pragma unroll
            for (int mt = 0; mt < 2; ++mt)
#pragma unroll
                for (int nt = 0; nt < 8; ++nt) {
                    int c = nt * 16 + m;
#pragma unroll
                    for (int reg = 0; reg < 4; ++reg) {
                        int r = mbase + mt * 16 + q * 4 + reg;
                        if (r < NN) {
                            float v = acc[mt][nt][reg];
                            buf[(size_t)r * 128 + c] = f2b(v);
                            s8[nt] += v;
                            ss8[nt] += v * v;
                        }
                    }
                }
#pragma unroll
            for (int nt = 0; nt < 8; ++nt) {
                s8[nt] += __shfl_xor(s8[nt], 16, 64);  s8[nt] += __shfl_xor(s8[nt], 32, 64);
                ss8[nt] += __shfl_xor(ss8[nt], 16, 64); ss8[nt] += __shfl_xor(ss8[nt], 32, 64);
            }
        }
        __syncthreads();
        float* stf = (float*)Bs;
        if (t < 256) stf[t] = 0.f;
        __syncthreads();
        if (active && (t & 63) < 16) {
#pragma unroll
            for (int nt = 0; nt < 8; ++nt) {
                int c = nt * 16 + (t & 15);
                atomicAdd(&stf[c], s8[nt]);
                atomicAdd(&stf[128 + c], ss8[nt]);
            }
        }
        __syncthreads();
        if (t < 256) atomicAdd(&sbnstat[t], stf[t]);
        __syncthreads();  // Bs reused next rep
    }
}

// ---------------- launch ----------------
extern "C" void kernel_launch(void* const* d_in, const int* in_sizes, int n_in,
                              void* d_out, int out_size, void* d_ws, size_t ws_size,
                              hipStream_t stream) {
    const float* x = (const float*)d_in[0];
    const int* ei = (const int*)d_in[1];
    const int* batch = (const int*)d_in[2];
    const float* gfeats = (const float*)d_in[3];
    const float *Wl[3], *Wr[3], *gma[3], *bta[3];
    for (int i = 0; i < 3; ++i) {
        Wl[i] = (const float*)d_in[4 + 5 * i];
        // d_in[5+5i] = bl (cancelled by BatchNorm; unused)
        Wr[i] = (const float*)d_in[6 + 5 * i];
        gma[i] = (const float*)d_in[7 + 5 * i];
        bta[i] = (const float*)d_in[8 + 5 * i];
    }
    const float* W1 = (const float*)d_in[19];
    const float* bs1 = (const float*)d_in[20];
    const float* W2 = (const float*)d_in[21];
    const float* bs2 = (const float*)d_in[22];
    const float* W3 = (const float*)d_in[23];
    const float* bs3 = (const float*)d_in[24];

    char* p = (char*)d_ws;
    auto alloc = [&](size_t bytes) -> char* {
        char* r = p;
        p += (bytes + 255) & ~(size_t)255;
        return r;
    };
    int* cnt = (int*)alloc(NN * 4);
    int* col = (int*)alloc((size_t)NN * CAP * 4);
    int* gstart = (int*)alloc(NG * 4);
    int* gend = (int*)alloc(NG * 4);
    float* bnstats = (float*)alloc(3 * 256 * 4);
    float* pool_sum = (float*)alloc(NG * HID * 4);
    int* pool_max = (int*)alloc(NG * HID * 4);
    unsigned short* Bp = (unsigned short*)alloc(3 * 32768 * 2);
    unsigned short* xb = (unsigned short*)alloc((size_t)NN * 128 * 2);
    unsigned short* b0 = (unsigned short*)alloc((size_t)NN * 128 * 2);
    unsigned short* b1 = (unsigned short*)alloc((size_t)NN * 128 * 2);
    unsigned short* hn0 = (unsigned short*)alloc((size_t)NN * 128 * 2);
    float* s_bn = (float*)alloc(256 * 4);  // probe scratch stats

    const int* srcv = ei;
    const int* dstv = ei + NE;

    k_setup<<<(NN * 64 + 255) / 256, 256, 0, stream>>>(
        x, xb, cnt, gstart, gend, bnstats, pool_sum, pool_max,
        Wl[0], Wr[0], Wl[1], Wr[1], Wl[2], Wr[2], Bp);
    k_bounds<<<(NN + 255) / 256, 256, 0, stream>>>(batch, gstart, gend);
    k_scatter<<<SC_CHUNKS * SC_NB, 256, 0, stream>>>(srcv, dstv, cnt, col);

    // layer 0: input xb (raw, no prev norm)
    k_agg<<<(NN + 15) / 16, 256, 0, stream>>>(xb, cnt, col, b0);
    k_gemm<<<GEMM_BLOCKS, 256, 0, stream>>>(b0, xb, Bp, bnstats);
    k_norm<<<NN * 16 / 256, 256, 0, stream>>>(b0, bnstats, gma[0], bta[0], hn0);
    // layer 1: input hn0 (post-norm materialized)
    k_agg<<<(NN + 15) / 16, 256, 0, stream>>>(hn0, cnt, col, b1);
    k_gemm<<<GEMM_BLOCKS, 256, 0, stream>>>(b1, hn0, Bp + 32768, bnstats + 256);
    k_norm<<<NN * 16 / 256, 256, 0, stream>>>(b1, bnstats + 256, gma[1], bta[1], xb);  // xb reused as hn1
    // layer 2: input xb (= hn1); output b0 (free after hn0 was made)
    k_agg<<<(NN + 15) / 16, 256, 0, stream>>>(xb, cnt, col, b0);
    k_gemm<<<GEMM_BLOCKS, 256, 0, stream>>>(b0, xb, Bp + 65536, bnstats + 512);

    k_pool<<<NG * 8, 256, 0, stream>>>(b0, gstart, gend, bnstats + 2 * 256, gma[2], bta[2],
                                       pool_sum, pool_max);
    k_head<<<NG, 128, 0, stream>>>(pool_sum, pool_max, gstart, gend, gfeats,
                                   W1, bs1, W2, bs2, W3, bs3, (float*)d_out);

    // -------- probe (scratch-only, after production output) --------
    // b1 = layer-1 pre-BN (fully rewritten by next iteration's layer-1 agg);
    // hn0 = layer-1 input. t_gemm = dur(p_gemm) / PR_GEMM.
    p_gemm<<<GEMM_BLOCKS, 256, 0, stream>>>(b1, hn0, Bp, s_bn);
}